// Round 7
// baseline (990.607 us; speedup 1.0000x reference)
//
#include <hip/hip_runtime.h>
#include <hip/hip_cooperative_groups.h>

namespace cg = cooperative_groups;

#define NN 1536
#define NE 49152
#define NM (NE + NN)      // edges + self loops = 50688
#define FIN 27
#define HD 64
#define LDIM 32
#define PP 1178880        // NN*(NN-1)/2

#define EL_OFF  (NN*FIN)            // 41472
#define MU_OFF  (EL_OFF + PP)       // 1220352
#define LV_OFF  (MU_OFF + NN*LDIM)  // 1269504
#define GMU_OFF (LV_OFF + NN*LDIM)  // 1318656
#define GLV_OFF (GMU_OFF + LDIM)    // 1318688

__device__ __forceinline__ float wsum(float v) {
#pragma unroll
  for (int m = 1; m < 64; m <<= 1) v += __shfl_xor(v, m, 64);
  return v;
}
__device__ __forceinline__ void wsum2(float& a, float& b) {
#pragma unroll
  for (int m = 1; m < 64; m <<= 1) {
    a += __shfl_xor(a, m, 64);
    b += __shfl_xor(b, m, 64);
  }
}
__device__ __forceinline__ float lnorm64(float x, float g, float b) {
  float s1 = x, s2 = x * x;
  wsum2(s1, s2);
  float mu = s1 * (1.0f / 64.0f);
  float var = fmaf(-mu, mu, s2 * (1.0f / 64.0f));
  return (x - mu) * rsqrtf(var + 1e-5f) * g + b;
}

struct GP {
  const float* x; const int* ei; const float* eps;
  const float *Wl1, *bl1, *Wr1, *br1, *att1, *bias1;
  const float *Wl2, *bl2, *Wr2, *br2, *att2, *bias2;
  const float *Wnm, *bnm, *Wnv, *bnv, *Wgm, *bgm, *Wgv, *bgv;
  const float *Wd1, *bd1, *g1, *b1, *Wd2, *bd2, *g2, *b2, *Wd3, *bd3;
  const float *We1, *be1, *lng, *lnb, *w2, *be2;
  const float *Wf1, *bf1, *gf, *bfv, *Wf2, *bf2;
  float *xl1, *xr1, *xl2, *xr2, *uu, *vv;
  float *A1, *A2, *D1, *D2, *gh;   // A1.. contiguous zero region
  float* out;
};

// one cooperative kernel; phases split by grid.sync()
__global__ __launch_bounds__(256, 4) void gvae_mono(GP p) {
  cg::grid_group grid = cg::this_grid();
  __shared__ __align__(16) float sh[8516];   // 34 KB: edge-tile U/V/C/cc (phase 5 only)
  const int t = threadIdx.x, b = blockIdx.x;
  const int NB = gridDim.x;
  const int wv = t >> 6, lane = t & 63;
  const int WSTRIDE = NB * 4;

  // ---------- P0: zero accumulators + GAT1 transform ----------
  {
    float4* z4 = (float4*)p.A1;
    const int nz4 = (2 * NN * HD + 2 * NN + HD) / 4;
    float4 zz = {0.f, 0.f, 0.f, 0.f};
    for (int e = b * 256 + t; e < nz4; e += NB * 256) z4[e] = zz;
    float bl = p.bl1[lane], br = p.br1[lane];
    for (int i = b + NB * wv; i < NN; i += WSTRIDE) {
      float xv = (lane < FIN) ? p.x[i * FIN + lane] : 0.f;
      float l0 = bl, l1 = 0.f, r0 = br, r1 = 0.f;
#pragma unroll
      for (int a = 0; a < FIN; a += 2) {
        float xa = __shfl(xv, a, 64);
        l0 = fmaf(xa, p.Wl1[a * HD + lane], l0);
        r0 = fmaf(xa, p.Wr1[a * HD + lane], r0);
        if (a + 1 < FIN) {
          float xb = __shfl(xv, a + 1, 64);
          l1 = fmaf(xb, p.Wl1[(a + 1) * HD + lane], l1);
          r1 = fmaf(xb, p.Wr1[(a + 1) * HD + lane], r1);
        }
      }
      p.xl1[i * HD + lane] = l0 + l1;
      p.xr1[i * HD + lane] = r0 + r1;
    }
  }
  __threadfence();
  grid.sync();

  // ---------- P1: GAT1 edge pass (shift-free softmax accumulate) ----------
  {
    float ak = p.att1[lane];
    for (int m = b + NB * wv; m < NM; m += WSTRIDE) {
      int src, dst;
      if (m < NE) { src = p.ei[m]; dst = p.ei[NE + m]; }
      else        { src = m - NE; dst = src; }
      float xls = p.xl1[src * HD + lane];
      float e = xls + p.xr1[dst * HD + lane];
      e = fmaxf(e, 0.2f * e);                 // leaky_relu(0.2)
      float w = expf(wsum(e * ak));           // wave-uniform
      atomicAdd(&p.A1[dst * HD + lane], w * xls);
      if (lane == 0) atomicAdd(&p.D1[dst], w);
    }
  }
  __threadfence();
  grid.sync();

  // ---------- P2: GAT2 transform (fused GAT1 epilogue) ----------
  {
    float hb = p.bias1[lane], bl = p.bl2[lane], br = p.br2[lane];
    for (int i = b + NB * wv; i < NN; i += WSTRIDE) {
      float xv = fmaxf(p.A1[i * HD + lane] / p.D1[i] + hb, 0.f);
      float l0 = bl, l1 = 0.f, r0 = br, r1 = 0.f;
#pragma unroll
      for (int a = 0; a < HD; a += 2) {
        float xa = __shfl(xv, a, 64);
        float xb = __shfl(xv, a + 1, 64);
        l0 = fmaf(xa, p.Wl2[a * HD + lane], l0);
        r0 = fmaf(xa, p.Wr2[a * HD + lane], r0);
        l1 = fmaf(xb, p.Wl2[(a + 1) * HD + lane], l1);
        r1 = fmaf(xb, p.Wr2[(a + 1) * HD + lane], r1);
      }
      p.xl2[i * HD + lane] = l0 + l1;
      p.xr2[i * HD + lane] = r0 + r1;
    }
  }
  __threadfence();
  grid.sync();

  // ---------- P3: GAT2 edge pass ----------
  {
    float ak = p.att2[lane];
    for (int m = b + NB * wv; m < NM; m += WSTRIDE) {
      int src, dst;
      if (m < NE) { src = p.ei[m]; dst = p.ei[NE + m]; }
      else        { src = m - NE; dst = src; }
      float xls = p.xl2[src * HD + lane];
      float e = xls + p.xr2[dst * HD + lane];
      e = fmaxf(e, 0.2f * e);
      float w = expf(wsum(e * ak));
      atomicAdd(&p.A2[dst * HD + lane], w * xls);
      if (lane == 0) atomicAdd(&p.D2[dst], w);
    }
  }
  __threadfence();
  grid.sync();

  // ---------- P4: fused node pipeline ----------
  {
    const int k = lane, kk = k & 31;
    const int kc = (k < FIN) ? k : (FIN - 1);
    for (int i = b + NB * wv; i < NN; i += WSTRIDE) {
      float h2k = fmaxf(p.A2[i * HD + k] / p.D2[i] + p.bias2[k], 0.f);
      atomicAdd(&p.gh[k], h2k * (1.0f / NN));

      // node_mu (lanes 0..31) / node_logvar (lanes 32..63)
      const float* W = (k < 32) ? p.Wnm : p.Wnv;
      float c0 = (k < 32) ? p.bnm[kk] : p.bnv[kk];
      float c1 = 0.f, c2 = 0.f, c3 = 0.f;
#pragma unroll
      for (int a = 0; a < HD; a += 4) {
        c0 = fmaf(__shfl(h2k, a, 64),     W[a * LDIM + kk],       c0);
        c1 = fmaf(__shfl(h2k, a + 1, 64), W[(a + 1) * LDIM + kk], c1);
        c2 = fmaf(__shfl(h2k, a + 2, 64), W[(a + 2) * LDIM + kk], c2);
        c3 = fmaf(__shfl(h2k, a + 3, 64), W[(a + 3) * LDIM + kk], c3);
      }
      float acc = (c0 + c1) + (c2 + c3);
      if (k < 32) p.out[MU_OFF + i * LDIM + kk] = acc;
      else        p.out[LV_OFF + i * LDIM + kk] = acc;

      // z = mu + eps*exp(0.5*logvar)
      float lv = __shfl(acc, k + 32, 64);
      float zk = acc + p.eps[i * LDIM + kk] * expf(0.5f * lv);

      // u/v for edge-pred factorization
      float u0 = p.be1[k], u1 = 0.f, v0 = 0.f, v1 = 0.f;
#pragma unroll
      for (int a = 0; a < LDIM; a += 2) {
        float za = __shfl(zk, a, 64);
        float zb = __shfl(zk, a + 1, 64);
        u0 = fmaf(za, p.We1[a * HD + k], u0);
        u1 = fmaf(zb, p.We1[(a + 1) * HD + k], u1);
        v0 = fmaf(za, p.We1[(a + LDIM) * HD + k], v0);
        v1 = fmaf(zb, p.We1[(a + 1 + LDIM) * HD + k], v1);
      }
      p.uu[i * HD + k] = u0 + u1;
      p.vv[i * HD + k] = v0 + v1;

      // decoder layer 1
      c0 = p.bd1[k]; c1 = 0.f; c2 = 0.f; c3 = 0.f;
#pragma unroll
      for (int a = 0; a < LDIM; a += 4) {
        c0 = fmaf(__shfl(zk, a, 64),     p.Wd1[a * HD + k],       c0);
        c1 = fmaf(__shfl(zk, a + 1, 64), p.Wd1[(a + 1) * HD + k], c1);
        c2 = fmaf(__shfl(zk, a + 2, 64), p.Wd1[(a + 2) * HD + k], c2);
        c3 = fmaf(__shfl(zk, a + 3, 64), p.Wd1[(a + 3) * HD + k], c3);
      }
      float nf1 = lnorm64(fmaxf((c0 + c1) + (c2 + c3), 0.f), p.g1[k], p.b1[k]);

      // decoder layer 2
      c0 = p.bd2[k]; c1 = 0.f; c2 = 0.f; c3 = 0.f;
#pragma unroll
      for (int a = 0; a < HD; a += 4) {
        c0 = fmaf(__shfl(nf1, a, 64),     p.Wd2[a * HD + k],       c0);
        c1 = fmaf(__shfl(nf1, a + 1, 64), p.Wd2[(a + 1) * HD + k], c1);
        c2 = fmaf(__shfl(nf1, a + 2, 64), p.Wd2[(a + 2) * HD + k], c2);
        c3 = fmaf(__shfl(nf1, a + 3, 64), p.Wd2[(a + 3) * HD + k], c3);
      }
      float nf2 = lnorm64(fmaxf((c0 + c1) + (c2 + c3), 0.f), p.g2[k], p.b2[k]);

      // decoder out (27 dims)
      c0 = 0.f; c1 = 0.f; c2 = 0.f; c3 = 0.f;
#pragma unroll
      for (int a = 0; a < HD; a += 4) {
        c0 = fmaf(__shfl(nf2, a, 64),     p.Wd3[a * FIN + kc],       c0);
        c1 = fmaf(__shfl(nf2, a + 1, 64), p.Wd3[(a + 1) * FIN + kc], c1);
        c2 = fmaf(__shfl(nf2, a + 2, 64), p.Wd3[(a + 2) * FIN + kc], c2);
        c3 = fmaf(__shfl(nf2, a + 3, 64), p.Wd3[(a + 3) * FIN + kc], c3);
      }
      float nf3 = (k < FIN) ? ((c0 + c1) + (c2 + c3) + p.bd3[kc]) : 0.f;

      // refinement
      c0 = p.bf1[k]; c1 = 0.f; c2 = 0.f; c3 = 0.f;
#pragma unroll
      for (int j = 0; j < FIN; j++) {
        float nj = __shfl(nf3, j, 64);
        c0 = fmaf(nj, p.Wf1[j * HD + k], c0);
      }
#pragma unroll
      for (int a = 0; a < HD; a += 4) {
        c0 = fmaf(__shfl(h2k, a, 64),     p.Wf1[(FIN + a) * HD + k],     c0);
        c1 = fmaf(__shfl(h2k, a + 1, 64), p.Wf1[(FIN + a + 1) * HD + k], c1);
        c2 = fmaf(__shfl(h2k, a + 2, 64), p.Wf1[(FIN + a + 2) * HD + k], c2);
        c3 = fmaf(__shfl(h2k, a + 3, 64), p.Wf1[(FIN + a + 3) * HD + k], c3);
      }
      float rr = lnorm64(fmaxf((c0 + c1) + (c2 + c3), 0.f), p.gf[k], p.bfv[k]);

      // node_features
      c0 = 0.f; c1 = 0.f; c2 = 0.f; c3 = 0.f;
#pragma unroll
      for (int a = 0; a < HD; a += 4) {
        c0 = fmaf(__shfl(rr, a, 64),     p.Wf2[a * FIN + kc],       c0);
        c1 = fmaf(__shfl(rr, a + 1, 64), p.Wf2[(a + 1) * FIN + kc], c1);
        c2 = fmaf(__shfl(rr, a + 2, 64), p.Wf2[(a + 2) * FIN + kc], c2);
        c3 = fmaf(__shfl(rr, a + 3, 64), p.Wf2[(a + 3) * FIN + kc], c3);
      }
      if (k < FIN) p.out[i * FIN + k] = (c0 + c1) + (c2 + c3) + p.bf2[kc];
    }
  }
  __threadfence();
  grid.sync();

  // ---------- P5: graph head (block 0, wave 3) + edge prediction tiles ----------
  if (b == 0 && wv == 3) {
    int kk = lane & 31;
    float ghk = p.gh[lane];
    const float* W = (lane < 32) ? p.Wgm : p.Wgv;
    float c0 = (lane < 32) ? p.bgm[kk] : p.bgv[kk];
    float c1 = 0.f, c2 = 0.f, c3 = 0.f;
#pragma unroll
    for (int a = 0; a < HD; a += 4) {
      c0 = fmaf(__shfl(ghk, a, 64),     W[a * LDIM + kk],       c0);
      c1 = fmaf(__shfl(ghk, a + 1, 64), W[(a + 1) * LDIM + kk], c1);
      c2 = fmaf(__shfl(ghk, a + 2, 64), W[(a + 2) * LDIM + kk], c2);
      c3 = fmaf(__shfl(ghk, a + 3, 64), W[(a + 3) * LDIM + kk], c3);
    }
    float acc = (c0 + c1) + (c2 + c3);
    if (lane < 32) p.out[GMU_OFF + kk] = acc;
    else           p.out[GLV_OFF + kk] = acc;
  }

  // tile LDS partitions
  float* U  = sh;                 // 64*64
  float* V  = sh + 4096;          // 64*68 (stride 68: conflict-free lane-varying b128)
  float* C  = sh + 4096 + 64 * 68;
  float* cc = C + 64;
  if (t < 64) {   // wave 0: logit-layer constants (tile-invariant)
    float ck = p.lng[t] * p.w2[t];
    C[t] = ck;
    float cb = p.lnb[t] * p.w2[t];
    float sC = wsum(ck);
    float sB = wsum(cb);
    if (t == 0) { cc[0] = sC; cc[1] = sB + p.be2[0]; }
  }

  for (int tt = b; tt < 300; tt += NB) {
    int rem = tt, bi = 0;
    while (rem >= 24 - bi) { rem -= 24 - bi; bi++; }   // upper-tri tile index
    int bj = bi + rem;
    const float4* u4p = (const float4*)(p.uu + bi * 64 * HD);
    const float4* v4p = (const float4*)(p.vv + bj * 64 * HD);
#pragma unroll
    for (int it = 0; it < 4; ++it) {
      int r = t + it * 256;
      int row = r >> 4, q = r & 15;
      float4 uu4 = u4p[r];
      *(float4*)&U[row * 64 + q * 4] = uu4;
      float4 vv4 = v4p[r];
      *(float4*)&V[row * 68 + q * 4] = vv4;
    }
    __syncthreads();
    float C1 = cc[0], C0 = cc[1];

    float S1[16], S2[16], Sc[16];
#pragma unroll
    for (int ii = 0; ii < 16; ii++) { S1[ii] = 0.f; S2[ii] = 0.f; Sc[ii] = 0.f; }
    const float* Ub = &U[(wv * 16) * 64];
    for (int k4 = 0; k4 < 16; k4++) {
      float4 v4 = *(const float4*)&V[lane * 68 + k4 * 4];
      float4 c4 = *(const float4*)&C[k4 * 4];
#pragma unroll
      for (int ii = 0; ii < 16; ii++) {
        float4 u4 = *(const float4*)&Ub[ii * 64 + k4 * 4];
        float t0 = fmaxf(u4.x + v4.x, 0.f);
        float t1 = fmaxf(u4.y + v4.y, 0.f);
        float t2 = fmaxf(u4.z + v4.z, 0.f);
        float t3 = fmaxf(u4.w + v4.w, 0.f);
        S1[ii] += (t0 + t1) + (t2 + t3);
        S2[ii] = fmaf(t0, t0, fmaf(t1, t1, fmaf(t2, t2, fmaf(t3, t3, S2[ii]))));
        Sc[ii] = fmaf(t0, c4.x, fmaf(t1, c4.y, fmaf(t2, c4.z, fmaf(t3, c4.w, Sc[ii]))));
      }
    }
    int j = bj * 64 + lane;
    const float inv64 = 1.0f / 64.0f;
#pragma unroll
    for (int ii = 0; ii < 16; ii++) {
      int i = bi * 64 + wv * 16 + ii;
      if (j > i) {
        int pbase = i * (2 * NN - i - 1) / 2 - i - 1;
        float mu = S1[ii] * inv64;
        float var = fmaf(-mu, mu, S2[ii] * inv64);
        float logit = (Sc[ii] - mu * C1) * rsqrtf(var + 1e-5f) + C0;
        p.out[EL_OFF + pbase + j] = logit;
      }
    }
    __syncthreads();   // protect U/V restage next iteration
  }
}

extern "C" void kernel_launch(void* const* d_in, const int* in_sizes, int n_in,
                              void* d_out, int out_size, void* d_ws, size_t ws_size,
                              hipStream_t stream) {
  GP p;
  p.x    = (const float*)d_in[0];
  p.ei   = (const int*)d_in[1];
  p.eps  = (const float*)d_in[2];
  // d_in[3] = eps_graph: z_graph unused downstream
  p.Wl1  = (const float*)d_in[4];  p.bl1 = (const float*)d_in[5];
  p.Wr1  = (const float*)d_in[6];  p.br1 = (const float*)d_in[7];
  p.att1 = (const float*)d_in[8];  p.bias1 = (const float*)d_in[9];
  p.Wl2  = (const float*)d_in[10]; p.bl2 = (const float*)d_in[11];
  p.Wr2  = (const float*)d_in[12]; p.br2 = (const float*)d_in[13];
  p.att2 = (const float*)d_in[14]; p.bias2 = (const float*)d_in[15];
  p.Wnm  = (const float*)d_in[16]; p.bnm = (const float*)d_in[17];
  p.Wnv  = (const float*)d_in[18]; p.bnv = (const float*)d_in[19];
  p.Wgm  = (const float*)d_in[20]; p.bgm = (const float*)d_in[21];
  p.Wgv  = (const float*)d_in[22]; p.bgv = (const float*)d_in[23];
  p.Wd1  = (const float*)d_in[24]; p.bd1 = (const float*)d_in[25];
  p.g1   = (const float*)d_in[26]; p.b1  = (const float*)d_in[27];
  p.Wd2  = (const float*)d_in[28]; p.bd2 = (const float*)d_in[29];
  p.g2   = (const float*)d_in[30]; p.b2  = (const float*)d_in[31];
  p.Wd3  = (const float*)d_in[32]; p.bd3 = (const float*)d_in[33];
  p.We1  = (const float*)d_in[34]; p.be1 = (const float*)d_in[35];
  p.lng  = (const float*)d_in[36]; p.lnb = (const float*)d_in[37];
  p.w2   = (const float*)d_in[38]; p.be2 = (const float*)d_in[39];
  p.Wf1  = (const float*)d_in[40]; p.bf1 = (const float*)d_in[41];
  p.gf   = (const float*)d_in[42]; p.bfv = (const float*)d_in[43];
  p.Wf2  = (const float*)d_in[44]; p.bf2 = (const float*)d_in[45];
  p.out  = (float*)d_out;

  float* fb = (float*)d_ws;
  p.xl1 = fb;
  p.xr1 = p.xl1 + NN * HD;
  p.xl2 = p.xr1 + NN * HD;
  p.xr2 = p.xl2 + NN * HD;
  p.uu  = p.xr2 + NN * HD;
  p.vv  = p.uu  + NN * HD;
  p.A1  = p.vv  + NN * HD;   // zero region start (zeroed in-kernel P0)
  p.A2  = p.A1  + NN * HD;
  p.D1  = p.A2  + NN * HD;
  p.D2  = p.D1  + NN;
  p.gh  = p.D2  + NN;        // 64 floats

  // size the cooperative grid (host-side queries: capture-safe, replay-free)
  int dev = 0;
  hipGetDevice(&dev);
  int numCU = 256;
  hipDeviceGetAttribute(&numCU, hipDeviceAttributeMultiprocessorCount, dev);
  int maxb = 0;
  hipOccupancyMaxActiveBlocksPerMultiprocessor(&maxb, (const void*)gvae_mono, 256, 0);
  if (maxb < 1) maxb = 1;
  int nb = maxb * numCU;
  if (nb > 2048) nb = 2048;

  void* kargs[] = { (void*)&p };
  hipLaunchCooperativeKernel((const void*)gvae_mono, dim3(nb), dim3(256),
                             kargs, 0, stream);
}

// Round 8
// 256.184 us; speedup vs baseline: 3.8668x; 3.8668x over previous
//
#include <hip/hip_runtime.h>

#define NN 1536
#define NE 49152
#define NM (NE + NN)      // edges + self loops = 50688
#define FIN 27
#define HD 64
#define LDIM 32
#define PP 1178880        // NN*(NN-1)/2

#define EL_OFF  (NN*FIN)            // 41472
#define MU_OFF  (EL_OFF + PP)       // 1220352
#define LV_OFF  (MU_OFF + NN*LDIM)  // 1269504
#define GMU_OFF (LV_OFF + NN*LDIM)  // 1318656
#define GLV_OFF (GMU_OFF + LDIM)    // 1318688

__device__ __forceinline__ float wsum(float v) {
#pragma unroll
  for (int m = 1; m < 64; m <<= 1) v += __shfl_xor(v, m, 64);
  return v;
}
__device__ __forceinline__ void wsum2(float& a, float& b) {
#pragma unroll
  for (int m = 1; m < 64; m <<= 1) {
    a += __shfl_xor(a, m, 64);
    b += __shfl_xor(b, m, 64);
  }
}
__device__ __forceinline__ float lnorm64(float x, float g, float b) {
  float s1 = x, s2 = x * x;
  wsum2(s1, s2);
  float mu = s1 * (1.0f / 64.0f);
  float var = fmaf(-mu, mu, s2 * (1.0f / 64.0f));
  return (x - mu) * rsqrtf(var + 1e-5f) * g + b;
}
// cooperative 256-thread float4 copy global -> LDS
__device__ __forceinline__ void cp4(float* dst, const float* __restrict__ src,
                                    int n4, int t) {
  const float4* s4 = (const float4*)src;
  float4* d4 = (float4*)dst;
  for (int e = t; e < n4; e += 256) d4[e] = s4[e];
}

// ---------------- linear transform -> (xl, xr), wave per node, W in LDS ----------------
// FUSE: input is (A, D) raw softmax accumulators; h = relu(A/D + hbias) first.
// ZERO: grid-stride zero of zbase[0..nz4*4) (the A/D/gh accumulator region).
template <int KIN, bool FUSE, bool ZERO>
__global__ __launch_bounds__(256) void gvae_xform(
    const float* __restrict__ in, const float* __restrict__ Dn,
    const float* __restrict__ hbias,
    const float* __restrict__ Wl, const float* __restrict__ bl,
    const float* __restrict__ Wr, const float* __restrict__ br,
    float* __restrict__ xl, float* __restrict__ xr,
    float* __restrict__ zbase, int nz4) {
  __shared__ __align__(16) float sWl[KIN * HD];
  __shared__ __align__(16) float sWr[KIN * HD];
  int t = threadIdx.x;
  if (ZERO) {
    float4 zz = {0.f, 0.f, 0.f, 0.f};
    float4* z4 = (float4*)zbase;
    for (int e = blockIdx.x * 256 + t; e < nz4; e += (NN / 4) * 256) z4[e] = zz;
  }
  cp4(sWl, Wl, KIN * 16, t);
  cp4(sWr, Wr, KIN * 16, t);
  int i = blockIdx.x * 4 + (t >> 6);
  int k = t & 63;
  float xv = (k < KIN) ? in[i * KIN + k] : 0.f;
  if (FUSE) xv = fmaxf(xv / Dn[i] + hbias[k], 0.f);
  float l0 = bl[k], l1 = 0.f, r0 = br[k], r1 = 0.f;
  __syncthreads();
#pragma unroll
  for (int a = 0; a < KIN; a += 2) {
    float xa = __shfl(xv, a, 64);
    l0 = fmaf(xa, sWl[a * HD + k], l0);
    r0 = fmaf(xa, sWr[a * HD + k], r0);
    if (a + 1 < KIN) {
      float xb = __shfl(xv, a + 1, 64);
      l1 = fmaf(xb, sWl[(a + 1) * HD + k], l1);
      r1 = fmaf(xb, sWr[(a + 1) * HD + k], r1);
    }
  }
  xl[i * HD + k] = l0 + l1;
  xr[i * HD + k] = r0 + r1;
}

// ---------------- GATv2 layer core: one edge-parallel pass ----------------
// softmax without max-shift (shift-invariant; |s| << 88 for this data):
// w = exp(s_e); A[dst] += w*xl[src]; D[dst] += w. Finalize in consumer.
__global__ __launch_bounds__(256) void gvae_edgepass(
    const int* __restrict__ ei,
    const float* __restrict__ xl, const float* __restrict__ xr,
    const float* __restrict__ att,
    float* __restrict__ A, float* __restrict__ D) {
  int m = blockIdx.x * 4 + (threadIdx.x >> 6);
  int lane = threadIdx.x & 63;
  int src, dst;
  if (m < NE) { src = ei[m]; dst = ei[NE + m]; }
  else        { src = m - NE; dst = src; }
  float xls = xl[src * HD + lane];
  float e = xls + xr[dst * HD + lane];
  e = fmaxf(e, 0.2f * e);                 // leaky_relu(0.2)
  float w = expf(wsum(e * att[lane]));    // wave-uniform
  atomicAdd(&A[dst * HD + lane], w * xls);
  if (lane == 0) atomicAdd(&D[dst], w);
}

// ---------------- fused node pipeline (big weights staged in LDS, 64 KB) ----------------
// LDS offsets (floats): only the 4 largest matrices; rest stay global (L2-hot).
#define oE1 0        // We1  64x64 = 4096
#define oD1 4096     // Wd1  32x64 = 2048
#define oD2 6144     // Wd2  64x64 = 4096
#define oF1 10240    // Wf1  91x64 = 5824
#define SWTOT 16064  // 62.75 KB -> 2 blocks/CU

__global__ __launch_bounds__(256, 2) void gvae_node(
    const float* __restrict__ A2, const float* __restrict__ D2,
    const float* __restrict__ bias2,
    const float* __restrict__ eps,
    const float* __restrict__ Wnm, const float* __restrict__ bnm,
    const float* __restrict__ Wnv, const float* __restrict__ bnv,
    const float* __restrict__ We1, const float* __restrict__ be1,
    const float* __restrict__ Wd1, const float* __restrict__ bd1,
    const float* __restrict__ g1, const float* __restrict__ b1,
    const float* __restrict__ Wd2, const float* __restrict__ bd2,
    const float* __restrict__ g2, const float* __restrict__ b2,
    const float* __restrict__ Wd3, const float* __restrict__ bd3,
    const float* __restrict__ Wf1, const float* __restrict__ bf1,
    const float* __restrict__ gf, const float* __restrict__ bfv,
    const float* __restrict__ Wf2, const float* __restrict__ bf2,
    float* __restrict__ uo, float* __restrict__ vo,
    float* __restrict__ gh, float* __restrict__ out) {
  __shared__ __align__(16) float sW[SWTOT];
  __shared__ float ghred[256];
  int t = threadIdx.x;
  cp4(sW + oE1, We1, 1024, t);
  cp4(sW + oD1, Wd1, 512, t);
  cp4(sW + oD2, Wd2, 1024, t);
  cp4(sW + oF1, Wf1, 1456, t);

  int i = blockIdx.x * 4 + (t >> 6);
  int k = t & 63;
  int kk = k & 31;
  int kc = (k < FIN) ? k : (FIN - 1);   // clamped index for [*,27] matrices
  float h2k = fmaxf(A2[i * HD + k] / D2[i] + bias2[k], 0.f);   // fused GAT-2 epilogue
  ghred[t] = h2k;
  __syncthreads();            // staging + ghred both ready
  if (t < 64) {               // one atomic per block per k
    float s = (ghred[t] + ghred[t + 64]) + (ghred[t + 128] + ghred[t + 192]);
    atomicAdd(&gh[t], s * (1.0f / NN));
  }

  // node_mu (lanes 0..31) / node_logvar (lanes 32..63) -- W from global (L2)
  const float* W = (k < 32) ? Wnm : Wnv;
  float c0 = (k < 32) ? bnm[kk] : bnv[kk];
  float c1 = 0.f, c2 = 0.f, c3 = 0.f;
#pragma unroll
  for (int a = 0; a < HD; a += 4) {
    c0 = fmaf(__shfl(h2k, a, 64),     W[a * LDIM + kk],       c0);
    c1 = fmaf(__shfl(h2k, a + 1, 64), W[(a + 1) * LDIM + kk], c1);
    c2 = fmaf(__shfl(h2k, a + 2, 64), W[(a + 2) * LDIM + kk], c2);
    c3 = fmaf(__shfl(h2k, a + 3, 64), W[(a + 3) * LDIM + kk], c3);
  }
  float acc = (c0 + c1) + (c2 + c3);
  if (k < 32) out[MU_OFF + i * LDIM + kk] = acc;
  else        out[LV_OFF + i * LDIM + kk] = acc;

  // z = mu + eps * exp(0.5*logvar)   (valid in lanes 0..31)
  float lv = __shfl(acc, k + 32, 64);
  float zk = acc + eps[i * LDIM + kk] * expf(0.5f * lv);

  // u = z@We1[:32] + be1 ; v = z@We1[32:]   (edge-pred factorization)
  float u0 = be1[k], u1 = 0.f, v0 = 0.f, v1 = 0.f;
#pragma unroll
  for (int a = 0; a < LDIM; a += 2) {
    float za = __shfl(zk, a, 64);
    float zb = __shfl(zk, a + 1, 64);
    u0 = fmaf(za, sW[oE1 + a * HD + k], u0);
    u1 = fmaf(zb, sW[oE1 + (a + 1) * HD + k], u1);
    v0 = fmaf(za, sW[oE1 + (a + LDIM) * HD + k], v0);
    v1 = fmaf(zb, sW[oE1 + (a + 1 + LDIM) * HD + k], v1);
  }
  uo[i * HD + k] = u0 + u1;
  vo[i * HD + k] = v0 + v1;

  // decoder layer 1: LN(relu(z@Wd1+bd1))
  c0 = bd1[k]; c1 = 0.f; c2 = 0.f; c3 = 0.f;
#pragma unroll
  for (int a = 0; a < LDIM; a += 4) {
    c0 = fmaf(__shfl(zk, a, 64),     sW[oD1 + a * HD + k],       c0);
    c1 = fmaf(__shfl(zk, a + 1, 64), sW[oD1 + (a + 1) * HD + k], c1);
    c2 = fmaf(__shfl(zk, a + 2, 64), sW[oD1 + (a + 2) * HD + k], c2);
    c3 = fmaf(__shfl(zk, a + 3, 64), sW[oD1 + (a + 3) * HD + k], c3);
  }
  float nf1 = lnorm64(fmaxf((c0 + c1) + (c2 + c3), 0.f), g1[k], b1[k]);

  // decoder layer 2
  c0 = bd2[k]; c1 = 0.f; c2 = 0.f; c3 = 0.f;
#pragma unroll
  for (int a = 0; a < HD; a += 4) {
    c0 = fmaf(__shfl(nf1, a, 64),     sW[oD2 + a * HD + k],       c0);
    c1 = fmaf(__shfl(nf1, a + 1, 64), sW[oD2 + (a + 1) * HD + k], c1);
    c2 = fmaf(__shfl(nf1, a + 2, 64), sW[oD2 + (a + 2) * HD + k], c2);
    c3 = fmaf(__shfl(nf1, a + 3, 64), sW[oD2 + (a + 3) * HD + k], c3);
  }
  float nf2 = lnorm64(fmaxf((c0 + c1) + (c2 + c3), 0.f), g2[k], b2[k]);

  // decoder out: nf3 = nf2@Wd3 + bd3 (27 dims) -- Wd3 global
  c0 = 0.f; c1 = 0.f; c2 = 0.f; c3 = 0.f;
#pragma unroll
  for (int a = 0; a < HD; a += 4) {
    c0 = fmaf(__shfl(nf2, a, 64),     Wd3[a * FIN + kc],       c0);
    c1 = fmaf(__shfl(nf2, a + 1, 64), Wd3[(a + 1) * FIN + kc], c1);
    c2 = fmaf(__shfl(nf2, a + 2, 64), Wd3[(a + 2) * FIN + kc], c2);
    c3 = fmaf(__shfl(nf2, a + 3, 64), Wd3[(a + 3) * FIN + kc], c3);
  }
  float nf3 = (k < FIN) ? ((c0 + c1) + (c2 + c3) + bd3[kc]) : 0.f;

  // refinement: LN(relu(cat(nf3, h2)@Wf1 + bf1))
  c0 = bf1[k]; c1 = 0.f; c2 = 0.f; c3 = 0.f;
#pragma unroll
  for (int j = 0; j < FIN; j++) {
    float nj = __shfl(nf3, j, 64);
    c0 = fmaf(nj, sW[oF1 + j * HD + k], c0);
  }
#pragma unroll
  for (int a = 0; a < HD; a += 4) {
    c0 = fmaf(__shfl(h2k, a, 64),     sW[oF1 + (FIN + a) * HD + k],     c0);
    c1 = fmaf(__shfl(h2k, a + 1, 64), sW[oF1 + (FIN + a + 1) * HD + k], c1);
    c2 = fmaf(__shfl(h2k, a + 2, 64), sW[oF1 + (FIN + a + 2) * HD + k], c2);
    c3 = fmaf(__shfl(h2k, a + 3, 64), sW[oF1 + (FIN + a + 3) * HD + k], c3);
  }
  float rr = lnorm64(fmaxf((c0 + c1) + (c2 + c3), 0.f), gf[k], bfv[k]);

  // node_features = rr@Wf2 + bf2 -- Wf2 global
  c0 = 0.f; c1 = 0.f; c2 = 0.f; c3 = 0.f;
#pragma unroll
  for (int a = 0; a < HD; a += 4) {
    c0 = fmaf(__shfl(rr, a, 64),     Wf2[a * FIN + kc],       c0);
    c1 = fmaf(__shfl(rr, a + 1, 64), Wf2[(a + 1) * FIN + kc], c1);
    c2 = fmaf(__shfl(rr, a + 2, 64), Wf2[(a + 2) * FIN + kc], c2);
    c3 = fmaf(__shfl(rr, a + 3, 64), Wf2[(a + 3) * FIN + kc], c3);
  }
  if (k < FIN) out[i * FIN + k] = (c0 + c1) + (c2 + c3) + bf2[kc];
}

// ---------------- edge prediction (300 upper-tri tiles) + fused graph head ----------------
// logit(i,j) = inv_sigma*(Sc - mu*C1) + C0 with t = relu(u_i + v_j),
// Sc = sum t_k c_k, c_k = lne_g_k*We2_k, C1 = sum c, C0 = sum lne_b*We2 + be2.
// lane = j_local (contiguous stores), 16 i-values per wave in registers.
__global__ __launch_bounds__(256) void gvae_edge(
    const float* __restrict__ u, const float* __restrict__ v,
    const float* __restrict__ lng, const float* __restrict__ lnb,
    const float* __restrict__ w2, const float* __restrict__ be2,
    const float* __restrict__ gh,
    const float* __restrict__ Wgm, const float* __restrict__ bgm,
    const float* __restrict__ Wgv, const float* __restrict__ bgv,
    float* __restrict__ out) {   // full out base
  __shared__ float U[64 * 64];   // read wave-uniform -> LDS broadcast
  __shared__ float V[64 * 68];   // lane-varying read, stride 68 (16B/lane sequential)
  __shared__ float C[64];
  __shared__ float cc[2];
  int t = threadIdx.x;
  int wv = t >> 6, lane = t & 63;

  // fused graph head: block 0, wave 3 (gh complete at kernel boundary)
  if (blockIdx.x == 0 && wv == 3) {
    int kk = lane & 31;
    float ghk = gh[lane];
    const float* W = (lane < 32) ? Wgm : Wgv;
    float c0 = (lane < 32) ? bgm[kk] : bgv[kk];
    float c1 = 0.f, c2 = 0.f, c3 = 0.f;
#pragma unroll
    for (int a = 0; a < HD; a += 4) {
      c0 = fmaf(__shfl(ghk, a, 64),     W[a * LDIM + kk],       c0);
      c1 = fmaf(__shfl(ghk, a + 1, 64), W[(a + 1) * LDIM + kk], c1);
      c2 = fmaf(__shfl(ghk, a + 2, 64), W[(a + 2) * LDIM + kk], c2);
      c3 = fmaf(__shfl(ghk, a + 3, 64), W[(a + 3) * LDIM + kk], c3);
    }
    float acc = (c0 + c1) + (c2 + c3);
    if (lane < 32) out[GMU_OFF + kk] = acc;
    else           out[GLV_OFF + kk] = acc;
  }

  // linear tile id -> upper-tri (bi, bj), bi<=bj, 300 tiles over 24x24
  int rem = blockIdx.x, bi = 0;
  while (rem >= 24 - bi) { rem -= 24 - bi; bi++; }
  int bj = bi + rem;

  const float4* u4p = (const float4*)(u + bi * 64 * HD);
  const float4* v4p = (const float4*)(v + bj * 64 * HD);
#pragma unroll
  for (int it = 0; it < 4; ++it) {
    int r = t + it * 256;
    int row = r >> 4, q = r & 15;
    float4 uu = u4p[r];
    *(float4*)&U[row * 64 + q * 4] = uu;
    float4 vv = v4p[r];
    *(float4*)&V[row * 68 + q * 4] = vv;
  }
  if (t < 64) {
    float ck = lng[t] * w2[t];
    C[t] = ck;
    float cb = lnb[t] * w2[t];
    float sC = wsum(ck);
    float sB = wsum(cb);
    if (t == 0) { cc[0] = sC; cc[1] = sB + be2[0]; }
  }
  __syncthreads();
  float C1 = cc[0], C0 = cc[1];

  float S1[16], S2[16], Sc[16];
#pragma unroll
  for (int ii = 0; ii < 16; ii++) { S1[ii] = 0.f; S2[ii] = 0.f; Sc[ii] = 0.f; }
  const float* Ub = &U[(wv * 16) * 64];
  for (int k4 = 0; k4 < 16; k4++) {
    float4 v4 = *(const float4*)&V[lane * 68 + k4 * 4];
    float4 c4 = *(const float4*)&C[k4 * 4];
#pragma unroll
    for (int ii = 0; ii < 16; ii++) {
      float4 u4 = *(const float4*)&Ub[ii * 64 + k4 * 4];
      float t0 = fmaxf(u4.x + v4.x, 0.f);
      float t1 = fmaxf(u4.y + v4.y, 0.f);
      float t2 = fmaxf(u4.z + v4.z, 0.f);
      float t3 = fmaxf(u4.w + v4.w, 0.f);
      S1[ii] += (t0 + t1) + (t2 + t3);
      S2[ii] = fmaf(t0, t0, fmaf(t1, t1, fmaf(t2, t2, fmaf(t3, t3, S2[ii]))));
      Sc[ii] = fmaf(t0, c4.x, fmaf(t1, c4.y, fmaf(t2, c4.z, fmaf(t3, c4.w, Sc[ii]))));
    }
  }
  int j = bj * 64 + lane;
  const float inv64 = 1.0f / 64.0f;
#pragma unroll
  for (int ii = 0; ii < 16; ii++) {
    int i = bi * 64 + wv * 16 + ii;
    if (j > i) {
      int pbase = i * (2 * NN - i - 1) / 2 - i - 1;
      float mu = S1[ii] * inv64;
      float var = fmaf(-mu, mu, S2[ii] * inv64);
      float logit = (Sc[ii] - mu * C1) * rsqrtf(var + 1e-5f) + C0;
      out[EL_OFF + pbase + j] = logit;   // contiguous across lanes
    }
  }
}

extern "C" void kernel_launch(void* const* d_in, const int* in_sizes, int n_in,
                              void* d_out, int out_size, void* d_ws, size_t ws_size,
                              hipStream_t stream) {
  const float* x    = (const float*)d_in[0];
  const int*   ei   = (const int*)d_in[1];
  const float* eps  = (const float*)d_in[2];
  // d_in[3] = eps_graph: z_graph computed but unused downstream -> skip
  const float* Wl1  = (const float*)d_in[4];
  const float* bl1  = (const float*)d_in[5];
  const float* Wr1  = (const float*)d_in[6];
  const float* br1  = (const float*)d_in[7];
  const float* att1 = (const float*)d_in[8];
  const float* bias1= (const float*)d_in[9];
  const float* Wl2  = (const float*)d_in[10];
  const float* bl2  = (const float*)d_in[11];
  const float* Wr2  = (const float*)d_in[12];
  const float* br2  = (const float*)d_in[13];
  const float* att2 = (const float*)d_in[14];
  const float* bias2= (const float*)d_in[15];
  const float* Wnm  = (const float*)d_in[16];
  const float* bnm  = (const float*)d_in[17];
  const float* Wnv  = (const float*)d_in[18];
  const float* bnv  = (const float*)d_in[19];
  const float* Wgm  = (const float*)d_in[20];
  const float* bgm  = (const float*)d_in[21];
  const float* Wgv  = (const float*)d_in[22];
  const float* bgv  = (const float*)d_in[23];
  const float* Wd1  = (const float*)d_in[24];
  const float* bd1  = (const float*)d_in[25];
  const float* ln1g = (const float*)d_in[26];
  const float* ln1b = (const float*)d_in[27];
  const float* Wd2  = (const float*)d_in[28];
  const float* bd2  = (const float*)d_in[29];
  const float* ln2g = (const float*)d_in[30];
  const float* ln2b = (const float*)d_in[31];
  const float* Wd3  = (const float*)d_in[32];
  const float* bd3  = (const float*)d_in[33];
  const float* We1  = (const float*)d_in[34];
  const float* be1  = (const float*)d_in[35];
  const float* lneg = (const float*)d_in[36];
  const float* lneb = (const float*)d_in[37];
  const float* We2  = (const float*)d_in[38];
  const float* be2  = (const float*)d_in[39];
  const float* Wf1  = (const float*)d_in[40];
  const float* bf1  = (const float*)d_in[41];
  const float* lnfg = (const float*)d_in[42];
  const float* lnfb = (const float*)d_in[43];
  const float* Wf2  = (const float*)d_in[44];
  const float* bf2  = (const float*)d_in[45];
  float* out = (float*)d_out;

  // workspace layout
  float* fb  = (float*)d_ws;
  float* xl1 = fb;
  float* xr1 = xl1 + NN * HD;
  float* xl2 = xr1 + NN * HD;
  float* xr2 = xl2 + NN * HD;
  float* uu  = xr2 + NN * HD;
  float* vv  = uu  + NN * HD;
  // zeroed region (contiguous, zeroed inside xform1): A1, A2, D1, D2, gh
  float* A1  = vv  + NN * HD;
  float* A2  = A1  + NN * HD;
  float* D1  = A2  + NN * HD;
  float* D2  = D1  + NN;
  float* gh  = D2  + NN;               // 64 floats
  int nz4 = (2 * NN * HD + 2 * NN + HD) / 4;

  gvae_xform<FIN, false, true><<<NN / 4, 256, 0, stream>>>(
      x, nullptr, nullptr, Wl1, bl1, Wr1, br1, xl1, xr1, A1, nz4);
  gvae_edgepass<<<NM / 4, 256, 0, stream>>>(ei, xl1, xr1, att1, A1, D1);
  gvae_xform<HD, true, false><<<NN / 4, 256, 0, stream>>>(
      A1, D1, bias1, Wl2, bl2, Wr2, br2, xl2, xr2, nullptr, 0);
  gvae_edgepass<<<NM / 4, 256, 0, stream>>>(ei, xl2, xr2, att2, A2, D2);

  gvae_node<<<NN / 4, 256, 0, stream>>>(A2, D2, bias2, eps,
      Wnm, bnm, Wnv, bnv, We1, be1,
      Wd1, bd1, ln1g, ln1b, Wd2, bd2, ln2g, ln2b, Wd3, bd3,
      Wf1, bf1, lnfg, lnfb, Wf2, bf2,
      uu, vv, gh, out);
  gvae_edge<<<300, 256, 0, stream>>>(uu, vv, lneg, lneb, We2, be2,
                                     gh, Wgm, bgm, Wgv, bgv, out);
}

// Round 9
// 253.411 us; speedup vs baseline: 3.9091x; 1.0109x over previous
//
#include <hip/hip_runtime.h>

#define NN 1536
#define NE 49152
#define NM (NE + NN)      // edges + self loops = 50688
#define FIN 27
#define HD 64
#define LDIM 32
#define PP 1178880        // NN*(NN-1)/2

#define EL_OFF  (NN*FIN)            // 41472
#define MU_OFF  (EL_OFF + PP)       // 1220352
#define LV_OFF  (MU_OFF + NN*LDIM)  // 1269504
#define GMU_OFF (LV_OFF + NN*LDIM)  // 1318656
#define GLV_OFF (GMU_OFF + LDIM)    // 1318688

#define EP_BLOCKS 1024    // edgepass grid: 4 blocks/CU, ~12 edges per wave

__device__ __forceinline__ float wsum(float v) {
#pragma unroll
  for (int m = 1; m < 64; m <<= 1) v += __shfl_xor(v, m, 64);
  return v;
}
__device__ __forceinline__ void wsum2(float& a, float& b) {
#pragma unroll
  for (int m = 1; m < 64; m <<= 1) {
    a += __shfl_xor(a, m, 64);
    b += __shfl_xor(b, m, 64);
  }
}
__device__ __forceinline__ float lnorm64(float x, float g, float b) {
  float s1 = x, s2 = x * x;
  wsum2(s1, s2);
  float mu = s1 * (1.0f / 64.0f);
  float var = fmaf(-mu, mu, s2 * (1.0f / 64.0f));
  return (x - mu) * rsqrtf(var + 1e-5f) * g + b;
}
// cooperative 256-thread float4 copy global -> LDS
__device__ __forceinline__ void cp4(float* dst, const float* __restrict__ src,
                                    int n4, int t) {
  const float4* s4 = (const float4*)src;
  float4* d4 = (float4*)dst;
  for (int e = t; e < n4; e += 256) d4[e] = s4[e];
}

// ---------------- linear transform -> (xl, xr), wave per node, W in LDS ----------------
// FUSE: input is (A, D) raw softmax accumulators; h = relu(A/D + hbias) first.
// ZERO: grid-stride zero of zbase[0..nz4*4) (the A/D/gh accumulator region).
template <int KIN, bool FUSE, bool ZERO>
__global__ __launch_bounds__(256) void gvae_xform(
    const float* __restrict__ in, const float* __restrict__ Dn,
    const float* __restrict__ hbias,
    const float* __restrict__ Wl, const float* __restrict__ bl,
    const float* __restrict__ Wr, const float* __restrict__ br,
    float* __restrict__ xl, float* __restrict__ xr,
    float* __restrict__ zbase, int nz4) {
  __shared__ __align__(16) float sWl[KIN * HD];
  __shared__ __align__(16) float sWr[KIN * HD];
  int t = threadIdx.x;
  if (ZERO) {
    float4 zz = {0.f, 0.f, 0.f, 0.f};
    float4* z4 = (float4*)zbase;
    for (int e = blockIdx.x * 256 + t; e < nz4; e += (NN / 4) * 256) z4[e] = zz;
  }
  cp4(sWl, Wl, KIN * 16, t);
  cp4(sWr, Wr, KIN * 16, t);
  int i = blockIdx.x * 4 + (t >> 6);
  int k = t & 63;
  float xv = (k < KIN) ? in[i * KIN + k] : 0.f;
  if (FUSE) xv = fmaxf(xv / Dn[i] + hbias[k], 0.f);
  float l0 = bl[k], l1 = 0.f, r0 = br[k], r1 = 0.f;
  __syncthreads();
#pragma unroll
  for (int a = 0; a < KIN; a += 2) {
    float xa = __shfl(xv, a, 64);
    l0 = fmaf(xa, sWl[a * HD + k], l0);
    r0 = fmaf(xa, sWr[a * HD + k], r0);
    if (a + 1 < KIN) {
      float xb = __shfl(xv, a + 1, 64);
      l1 = fmaf(xb, sWl[(a + 1) * HD + k], l1);
      r1 = fmaf(xb, sWr[(a + 1) * HD + k], r1);
    }
  }
  xl[i * HD + k] = l0 + l1;
  xr[i * HD + k] = r0 + r1;
}

// ---------------- GATv2 layer core: one edge-parallel pass (grid-stride) ----------------
// softmax without max-shift (shift-invariant; |s| << 88 for this data):
// w = exp(s_e); A[dst] += w*xl[src]; D[dst] += w. Finalize in consumer.
// Fat blocks: EP_BLOCKS blocks, each wave loops ~NM/(EP_BLOCKS*4) edges.
__global__ __launch_bounds__(256) void gvae_edgepass(
    const int* __restrict__ ei,
    const float* __restrict__ xl, const float* __restrict__ xr,
    const float* __restrict__ att,
    float* __restrict__ A, float* __restrict__ D) {
  int wid = blockIdx.x * 4 + (threadIdx.x >> 6);
  int lane = threadIdx.x & 63;
  const int NW = EP_BLOCKS * 4;
  float ak = att[lane];
#pragma unroll 2
  for (int m = wid; m < NM; m += NW) {
    int src, dst;
    if (m < NE) { src = ei[m]; dst = ei[NE + m]; }
    else        { src = m - NE; dst = src; }
    float xls = xl[src * HD + lane];
    float e = xls + xr[dst * HD + lane];
    e = fmaxf(e, 0.2f * e);                 // leaky_relu(0.2)
    float w = expf(wsum(e * ak));           // wave-uniform
    atomicAdd(&A[dst * HD + lane], w * xls);
    if (lane == 0) atomicAdd(&D[dst], w);
  }
}

// ---------------- fused node pipeline (big weights staged in LDS, 64 KB) ----------------
// LDS offsets (floats): only the 4 largest matrices; rest stay global (L2-hot).
#define oE1 0        // We1  64x64 = 4096
#define oD1 4096     // Wd1  32x64 = 2048
#define oD2 6144     // Wd2  64x64 = 4096
#define oF1 10240    // Wf1  91x64 = 5824
#define SWTOT 16064  // 62.75 KB -> 2 blocks/CU

__global__ __launch_bounds__(256, 2) void gvae_node(
    const float* __restrict__ A2, const float* __restrict__ D2,
    const float* __restrict__ bias2,
    const float* __restrict__ eps,
    const float* __restrict__ Wnm, const float* __restrict__ bnm,
    const float* __restrict__ Wnv, const float* __restrict__ bnv,
    const float* __restrict__ We1, const float* __restrict__ be1,
    const float* __restrict__ Wd1, const float* __restrict__ bd1,
    const float* __restrict__ g1, const float* __restrict__ b1,
    const float* __restrict__ Wd2, const float* __restrict__ bd2,
    const float* __restrict__ g2, const float* __restrict__ b2,
    const float* __restrict__ Wd3, const float* __restrict__ bd3,
    const float* __restrict__ Wf1, const float* __restrict__ bf1,
    const float* __restrict__ gf, const float* __restrict__ bfv,
    const float* __restrict__ Wf2, const float* __restrict__ bf2,
    float* __restrict__ uo, float* __restrict__ vo,
    float* __restrict__ gh, float* __restrict__ out) {
  __shared__ __align__(16) float sW[SWTOT];
  __shared__ float ghred[256];
  int t = threadIdx.x;
  cp4(sW + oE1, We1, 1024, t);
  cp4(sW + oD1, Wd1, 512, t);
  cp4(sW + oD2, Wd2, 1024, t);
  cp4(sW + oF1, Wf1, 1456, t);

  int i = blockIdx.x * 4 + (t >> 6);
  int k = t & 63;
  int kk = k & 31;
  int kc = (k < FIN) ? k : (FIN - 1);   // clamped index for [*,27] matrices
  float h2k = fmaxf(A2[i * HD + k] / D2[i] + bias2[k], 0.f);   // fused GAT-2 epilogue
  ghred[t] = h2k;
  __syncthreads();            // staging + ghred both ready
  if (t < 64) {               // one atomic per block per k
    float s = (ghred[t] + ghred[t + 64]) + (ghred[t + 128] + ghred[t + 192]);
    atomicAdd(&gh[t], s * (1.0f / NN));
  }

  // node_mu (lanes 0..31) / node_logvar (lanes 32..63) -- W from global (L2)
  const float* W = (k < 32) ? Wnm : Wnv;
  float c0 = (k < 32) ? bnm[kk] : bnv[kk];
  float c1 = 0.f, c2 = 0.f, c3 = 0.f;
#pragma unroll
  for (int a = 0; a < HD; a += 4) {
    c0 = fmaf(__shfl(h2k, a, 64),     W[a * LDIM + kk],       c0);
    c1 = fmaf(__shfl(h2k, a + 1, 64), W[(a + 1) * LDIM + kk], c1);
    c2 = fmaf(__shfl(h2k, a + 2, 64), W[(a + 2) * LDIM + kk], c2);
    c3 = fmaf(__shfl(h2k, a + 3, 64), W[(a + 3) * LDIM + kk], c3);
  }
  float acc = (c0 + c1) + (c2 + c3);
  if (k < 32) out[MU_OFF + i * LDIM + kk] = acc;
  else        out[LV_OFF + i * LDIM + kk] = acc;

  // z = mu + eps * exp(0.5*logvar)   (valid in lanes 0..31)
  float lv = __shfl(acc, k + 32, 64);
  float zk = acc + eps[i * LDIM + kk] * expf(0.5f * lv);

  // u = z@We1[:32] + be1 ; v = z@We1[32:]   (edge-pred factorization)
  float u0 = be1[k], u1 = 0.f, v0 = 0.f, v1 = 0.f;
#pragma unroll
  for (int a = 0; a < LDIM; a += 2) {
    float za = __shfl(zk, a, 64);
    float zb = __shfl(zk, a + 1, 64);
    u0 = fmaf(za, sW[oE1 + a * HD + k], u0);
    u1 = fmaf(zb, sW[oE1 + (a + 1) * HD + k], u1);
    v0 = fmaf(za, sW[oE1 + (a + LDIM) * HD + k], v0);
    v1 = fmaf(zb, sW[oE1 + (a + 1 + LDIM) * HD + k], v1);
  }
  uo[i * HD + k] = u0 + u1;
  vo[i * HD + k] = v0 + v1;

  // decoder layer 1: LN(relu(z@Wd1+bd1))
  c0 = bd1[k]; c1 = 0.f; c2 = 0.f; c3 = 0.f;
#pragma unroll
  for (int a = 0; a < LDIM; a += 4) {
    c0 = fmaf(__shfl(zk, a, 64),     sW[oD1 + a * HD + k],       c0);
    c1 = fmaf(__shfl(zk, a + 1, 64), sW[oD1 + (a + 1) * HD + k], c1);
    c2 = fmaf(__shfl(zk, a + 2, 64), sW[oD1 + (a + 2) * HD + k], c2);
    c3 = fmaf(__shfl(zk, a + 3, 64), sW[oD1 + (a + 3) * HD + k], c3);
  }
  float nf1 = lnorm64(fmaxf((c0 + c1) + (c2 + c3), 0.f), g1[k], b1[k]);

  // decoder layer 2
  c0 = bd2[k]; c1 = 0.f; c2 = 0.f; c3 = 0.f;
#pragma unroll
  for (int a = 0; a < HD; a += 4) {
    c0 = fmaf(__shfl(nf1, a, 64),     sW[oD2 + a * HD + k],       c0);
    c1 = fmaf(__shfl(nf1, a + 1, 64), sW[oD2 + (a + 1) * HD + k], c1);
    c2 = fmaf(__shfl(nf1, a + 2, 64), sW[oD2 + (a + 2) * HD + k], c2);
    c3 = fmaf(__shfl(nf1, a + 3, 64), sW[oD2 + (a + 3) * HD + k], c3);
  }
  float nf2 = lnorm64(fmaxf((c0 + c1) + (c2 + c3), 0.f), g2[k], b2[k]);

  // decoder out: nf3 = nf2@Wd3 + bd3 (27 dims) -- Wd3 global
  c0 = 0.f; c1 = 0.f; c2 = 0.f; c3 = 0.f;
#pragma unroll
  for (int a = 0; a < HD; a += 4) {
    c0 = fmaf(__shfl(nf2, a, 64),     Wd3[a * FIN + kc],       c0);
    c1 = fmaf(__shfl(nf2, a + 1, 64), Wd3[(a + 1) * FIN + kc], c1);
    c2 = fmaf(__shfl(nf2, a + 2, 64), Wd3[(a + 2) * FIN + kc], c2);
    c3 = fmaf(__shfl(nf2, a + 3, 64), Wd3[(a + 3) * FIN + kc], c3);
  }
  float nf3 = (k < FIN) ? ((c0 + c1) + (c2 + c3) + bd3[kc]) : 0.f;

  // refinement: LN(relu(cat(nf3, h2)@Wf1 + bf1))
  c0 = bf1[k]; c1 = 0.f; c2 = 0.f; c3 = 0.f;
#pragma unroll
  for (int j = 0; j < FIN; j++) {
    float nj = __shfl(nf3, j, 64);
    c0 = fmaf(nj, sW[oF1 + j * HD + k], c0);
  }
#pragma unroll
  for (int a = 0; a < HD; a += 4) {
    c0 = fmaf(__shfl(h2k, a, 64),     sW[oF1 + (FIN + a) * HD + k],     c0);
    c1 = fmaf(__shfl(h2k, a + 1, 64), sW[oF1 + (FIN + a + 1) * HD + k], c1);
    c2 = fmaf(__shfl(h2k, a + 2, 64), sW[oF1 + (FIN + a + 2) * HD + k], c2);
    c3 = fmaf(__shfl(h2k, a + 3, 64), sW[oF1 + (FIN + a + 3) * HD + k], c3);
  }
  float rr = lnorm64(fmaxf((c0 + c1) + (c2 + c3), 0.f), gf[k], bfv[k]);

  // node_features = rr@Wf2 + bf2 -- Wf2 global
  c0 = 0.f; c1 = 0.f; c2 = 0.f; c3 = 0.f;
#pragma unroll
  for (int a = 0; a < HD; a += 4) {
    c0 = fmaf(__shfl(rr, a, 64),     Wf2[a * FIN + kc],       c0);
    c1 = fmaf(__shfl(rr, a + 1, 64), Wf2[(a + 1) * FIN + kc], c1);
    c2 = fmaf(__shfl(rr, a + 2, 64), Wf2[(a + 2) * FIN + kc], c2);
    c3 = fmaf(__shfl(rr, a + 3, 64), Wf2[(a + 3) * FIN + kc], c3);
  }
  if (k < FIN) out[i * FIN + k] = (c0 + c1) + (c2 + c3) + bf2[kc];
}

// ---------------- edge prediction (300 upper-tri tiles) + fused graph head ----------------
__global__ __launch_bounds__(256) void gvae_edge(
    const float* __restrict__ u, const float* __restrict__ v,
    const float* __restrict__ lng, const float* __restrict__ lnb,
    const float* __restrict__ w2, const float* __restrict__ be2,
    const float* __restrict__ gh,
    const float* __restrict__ Wgm, const float* __restrict__ bgm,
    const float* __restrict__ Wgv, const float* __restrict__ bgv,
    float* __restrict__ out) {   // full out base
  __shared__ float U[64 * 64];   // read wave-uniform -> LDS broadcast
  __shared__ float V[64 * 68];   // lane-varying read, stride 68 (16B/lane sequential)
  __shared__ float C[64];
  __shared__ float cc[2];
  int t = threadIdx.x;
  int wv = t >> 6, lane = t & 63;

  // fused graph head: block 0, wave 3 (gh complete at kernel boundary)
  if (blockIdx.x == 0 && wv == 3) {
    int kk = lane & 31;
    float ghk = gh[lane];
    const float* W = (lane < 32) ? Wgm : Wgv;
    float c0 = (lane < 32) ? bgm[kk] : bgv[kk];
    float c1 = 0.f, c2 = 0.f, c3 = 0.f;
#pragma unroll
    for (int a = 0; a < HD; a += 4) {
      c0 = fmaf(__shfl(ghk, a, 64),     W[a * LDIM + kk],       c0);
      c1 = fmaf(__shfl(ghk, a + 1, 64), W[(a + 1) * LDIM + kk], c1);
      c2 = fmaf(__shfl(ghk, a + 2, 64), W[(a + 2) * LDIM + kk], c2);
      c3 = fmaf(__shfl(ghk, a + 3, 64), W[(a + 3) * LDIM + kk], c3);
    }
    float acc = (c0 + c1) + (c2 + c3);
    if (lane < 32) out[GMU_OFF + kk] = acc;
    else           out[GLV_OFF + kk] = acc;
  }

  // linear tile id -> upper-tri (bi, bj), bi<=bj, 300 tiles over 24x24
  int rem = blockIdx.x, bi = 0;
  while (rem >= 24 - bi) { rem -= 24 - bi; bi++; }
  int bj = bi + rem;

  const float4* u4p = (const float4*)(u + bi * 64 * HD);
  const float4* v4p = (const float4*)(v + bj * 64 * HD);
#pragma unroll
  for (int it = 0; it < 4; ++it) {
    int r = t + it * 256;
    int row = r >> 4, q = r & 15;
    float4 uu = u4p[r];
    *(float4*)&U[row * 64 + q * 4] = uu;
    float4 vv = v4p[r];
    *(float4*)&V[row * 68 + q * 4] = vv;
  }
  if (t < 64) {
    float ck = lng[t] * w2[t];
    C[t] = ck;
    float cb = lnb[t] * w2[t];
    float sC = wsum(ck);
    float sB = wsum(cb);
    if (t == 0) { cc[0] = sC; cc[1] = sB + be2[0]; }
  }
  __syncthreads();
  float C1 = cc[0], C0 = cc[1];

  float S1[16], S2[16], Sc[16];
#pragma unroll
  for (int ii = 0; ii < 16; ii++) { S1[ii] = 0.f; S2[ii] = 0.f; Sc[ii] = 0.f; }
  const float* Ub = &U[(wv * 16) * 64];
  for (int k4 = 0; k4 < 16; k4++) {
    float4 v4 = *(const float4*)&V[lane * 68 + k4 * 4];
    float4 c4 = *(const float4*)&C[k4 * 4];
#pragma unroll
    for (int ii = 0; ii < 16; ii++) {
      float4 u4 = *(const float4*)&Ub[ii * 64 + k4 * 4];
      float t0 = fmaxf(u4.x + v4.x, 0.f);
      float t1 = fmaxf(u4.y + v4.y, 0.f);
      float t2 = fmaxf(u4.z + v4.z, 0.f);
      float t3 = fmaxf(u4.w + v4.w, 0.f);
      S1[ii] += (t0 + t1) + (t2 + t3);
      S2[ii] = fmaf(t0, t0, fmaf(t1, t1, fmaf(t2, t2, fmaf(t3, t3, S2[ii]))));
      Sc[ii] = fmaf(t0, c4.x, fmaf(t1, c4.y, fmaf(t2, c4.z, fmaf(t3, c4.w, Sc[ii]))));
    }
  }
  int j = bj * 64 + lane;
  const float inv64 = 1.0f / 64.0f;
#pragma unroll
  for (int ii = 0; ii < 16; ii++) {
    int i = bi * 64 + wv * 16 + ii;
    if (j > i) {
      int pbase = i * (2 * NN - i - 1) / 2 - i - 1;
      float mu = S1[ii] * inv64;
      float var = fmaf(-mu, mu, S2[ii] * inv64);
      float logit = (Sc[ii] - mu * C1) * rsqrtf(var + 1e-5f) + C0;
      out[EL_OFF + pbase + j] = logit;   // contiguous across lanes
    }
  }
}

extern "C" void kernel_launch(void* const* d_in, const int* in_sizes, int n_in,
                              void* d_out, int out_size, void* d_ws, size_t ws_size,
                              hipStream_t stream) {
  const float* x    = (const float*)d_in[0];
  const int*   ei   = (const int*)d_in[1];
  const float* eps  = (const float*)d_in[2];
  // d_in[3] = eps_graph: z_graph computed but unused downstream -> skip
  const float* Wl1  = (const float*)d_in[4];
  const float* bl1  = (const float*)d_in[5];
  const float* Wr1  = (const float*)d_in[6];
  const float* br1  = (const float*)d_in[7];
  const float* att1 = (const float*)d_in[8];
  const float* bias1= (const float*)d_in[9];
  const float* Wl2  = (const float*)d_in[10];
  const float* bl2  = (const float*)d_in[11];
  const float* Wr2  = (const float*)d_in[12];
  const float* br2  = (const float*)d_in[13];
  const float* att2 = (const float*)d_in[14];
  const float* bias2= (const float*)d_in[15];
  const float* Wnm  = (const float*)d_in[16];
  const float* bnm  = (const float*)d_in[17];
  const float* Wnv  = (const float*)d_in[18];
  const float* bnv  = (const float*)d_in[19];
  const float* Wgm  = (const float*)d_in[20];
  const float* bgm  = (const float*)d_in[21];
  const float* Wgv  = (const float*)d_in[22];
  const float* bgv  = (const float*)d_in[23];
  const float* Wd1  = (const float*)d_in[24];
  const float* bd1  = (const float*)d_in[25];
  const float* ln1g = (const float*)d_in[26];
  const float* ln1b = (const float*)d_in[27];
  const float* Wd2  = (const float*)d_in[28];
  const float* bd2  = (const float*)d_in[29];
  const float* ln2g = (const float*)d_in[30];
  const float* ln2b = (const float*)d_in[31];
  const float* Wd3  = (const float*)d_in[32];
  const float* bd3  = (const float*)d_in[33];
  const float* We1  = (const float*)d_in[34];
  const float* be1  = (const float*)d_in[35];
  const float* lneg = (const float*)d_in[36];
  const float* lneb = (const float*)d_in[37];
  const float* We2  = (const float*)d_in[38];
  const float* be2  = (const float*)d_in[39];
  const float* Wf1  = (const float*)d_in[40];
  const float* bf1  = (const float*)d_in[41];
  const float* lnfg = (const float*)d_in[42];
  const float* lnfb = (const float*)d_in[43];
  const float* Wf2  = (const float*)d_in[44];
  const float* bf2  = (const float*)d_in[45];
  float* out = (float*)d_out;

  // workspace layout
  float* fb  = (float*)d_ws;
  float* xl1 = fb;
  float* xr1 = xl1 + NN * HD;
  float* xl2 = xr1 + NN * HD;
  float* xr2 = xl2 + NN * HD;
  float* uu  = xr2 + NN * HD;
  float* vv  = uu  + NN * HD;
  // zeroed region (contiguous, zeroed inside xform1): A1, A2, D1, D2, gh
  float* A1  = vv  + NN * HD;
  float* A2  = A1  + NN * HD;
  float* D1  = A2  + NN * HD;
  float* D2  = D1  + NN;
  float* gh  = D2  + NN;               // 64 floats
  int nz4 = (2 * NN * HD + 2 * NN + HD) / 4;

  gvae_xform<FIN, false, true><<<NN / 4, 256, 0, stream>>>(
      x, nullptr, nullptr, Wl1, bl1, Wr1, br1, xl1, xr1, A1, nz4);
  gvae_edgepass<<<EP_BLOCKS, 256, 0, stream>>>(ei, xl1, xr1, att1, A1, D1);
  gvae_xform<HD, true, false><<<NN / 4, 256, 0, stream>>>(
      A1, D1, bias1, Wl2, bl2, Wr2, br2, xl2, xr2, nullptr, 0);
  gvae_edgepass<<<EP_BLOCKS, 256, 0, stream>>>(ei, xl2, xr2, att2, A2, D2);

  gvae_node<<<NN / 4, 256, 0, stream>>>(A2, D2, bias2, eps,
      Wnm, bnm, Wnv, bnv, We1, be1,
      Wd1, bd1, ln1g, ln1b, Wd2, bd2, ln2g, ln2b, Wd3, bd3,
      Wf1, bf1, lnfg, lnfb, Wf2, bf2,
      uu, vv, gh, out);
  gvae_edge<<<300, 256, 0, stream>>>(uu, vv, lneg, lneb, We2, be2,
                                     gh, Wgm, bgm, Wgv, bgv, out);
}